// Round 6
// baseline (1159.357 us; speedup 1.0000x reference)
//
#include <hip/hip_runtime.h>

// Problem constants (from reference): 16 clouds x 4096 pts, sample 1024, D=512
#define N_PER   4096
#define M_SAMP  1024
#define B_CL    16
#define D_FEAT  512
#define TPB     256
#define NWAVE   (TPB / 64)      // 4 waves
#define PPT     (N_PER / TPB)   // 16 points per thread
#define NPAIR   (PPT / 2)       // 8 packed pairs per thread
#define CPB     2               // clouds per block (tail amortized over 2 steps)

typedef float v2f __attribute__((ext_vector_type(2)));

// ---------------------------------------------------------------------------
// u32 DPP max combine (value-only wave reduce). Lanes not supplied by the
// pattern combine with themselves (old == own value -> no-op).
// ---------------------------------------------------------------------------
template <int CTRL>
__device__ __forceinline__ unsigned dpp_maxu(unsigned v) {
    unsigned o = (unsigned)__builtin_amdgcn_update_dpp((int)v, (int)v, CTRL, 0xF, 0xF, false);
    return (o > v) ? o : v;
}

// ---------------------------------------------------------------------------
// FPS, two clouds per block. Per-cloud step structure is IDENTICAL to the
// verified 549us R2 kernel (every within-step rearrangement measured worse:
// R1 spin +29%, R3 2w/SIMD +7%, R4 divergent coord ship +14%, R5 pre-barrier
// coord ship +10%). The gain here is structural: the ~600cy serial tail
// (barrier rendezvous + key round + dependent spos read) is paid ONCE per
// round serving TWO independent FPS steps, and cloud B's inner loop issues
// into cloud A's reduce-chain latency bubbles (independent streams).
//
// Exactness per cloud (unchanged):
//  - distance math contract(off), same op order -> bit-exact d2 chain
//  - value-only in-loop max via v_max3_f32; first-occurrence index by
//    descending equality scan (min j wins)
//  - wave reduce: 6-stage u32 DPP max on float bits (all dist >= 0)
//  - winner lane via readlane(63) -> ballot -> ctz (lane order == idx order)
//  - cross-wave merge via u64 keys (dist bits << 32 | (4095 - idx)):
//    max key == max dist, tie -> smaller idx (jnp.argmax semantics)
// ---------------------------------------------------------------------------
__global__ __launch_bounds__(TPB)
__attribute__((amdgpu_waves_per_eu(1, 1)))
void fps_kernel(const float* __restrict__ pos, int* __restrict__ sidx) {
    __shared__ float4             spos[CPB][N_PER];      // 2 x 64 KiB coord tables
    __shared__ unsigned long long swk[CPB][2][NWAVE];    // per-cloud dbuf wave keys
    __shared__ int                sloc[CPB][M_SAMP];     // per-cloud sampled idx

    const int tid  = threadIdx.x;
    const int wave = tid >> 6;
    const int lane = tid & 63;
    const int base = tid * PPT;

    // per-cloud register state (c and p always compile-time after unroll)
    v2f px2[CPB][NPAIR], py2[CPB][NPAIR], pz2[CPB][NPAIR], dist2[CPB][NPAIR];
    float lx[CPB], ly[CPB], lz[CPB];

#pragma unroll
    for (int c = 0; c < CPB; ++c) {
        const int cloud = blockIdx.x * CPB + c;
        const float* posb = pos + (size_t)cloud * N_PER * 3;
        float f[48];
        const float4* posb4 = (const float4*)posb + tid * 12;
#pragma unroll
        for (int v = 0; v < 12; ++v) {
            float4 t = posb4[v];
            f[4 * v + 0] = t.x; f[4 * v + 1] = t.y;
            f[4 * v + 2] = t.z; f[4 * v + 3] = t.w;
        }
#pragma unroll
        for (int p = 0; p < NPAIR; ++p) {
            px2[c][p] = (v2f){f[6 * p + 0], f[6 * p + 3]};
            py2[c][p] = (v2f){f[6 * p + 1], f[6 * p + 4]};
            pz2[c][p] = (v2f){f[6 * p + 2], f[6 * p + 5]};
            dist2[c][p] = (v2f){1e30f, 1e30f};
        }
#pragma unroll
        for (int j = 0; j < PPT; ++j)
            spos[c][base + j] = make_float4(f[3 * j], f[3 * j + 1], f[3 * j + 2], 0.0f);
        lx[c] = posb[0]; ly[c] = posb[1]; lz[c] = posb[2];   // start point = local 0
        if (tid == 0) sloc[c][0] = 0;
    }
    __syncthreads();   // spos visible

    for (int s = 1; s < M_SAMP; ++s) {
        const int buf = s & 1;

        // --- pre-barrier: both clouds' inner loops + wave reduces.
        // Independent streams: B's pk stream fills A's DPP/scalar bubbles.
#pragma unroll
        for (int c = 0; c < CPB; ++c) {
            float bv = -1.0f;     // all dist >= 0, so always beaten
            v2f lxv = {lx[c], lx[c]}, lyv = {ly[c], ly[c]}, lzv = {lz[c], lz[c]};
#pragma unroll
            for (int p = 0; p < NPAIR; ++p) {
#pragma clang fp contract(off)
                v2f dx = px2[c][p] - lxv;
                v2f dy = py2[c][p] - lyv;
                v2f dz = pz2[c][p] - lzv;
                v2f d2 = dx * dx + dy * dy + dz * dz;      // contract off: exact jnp order
                v2f dn = __builtin_elementwise_min(dist2[c][p], d2);
                dist2[c][p] = dn;
                // value-only running max: one v_max3_f32 per pair
                asm("v_max3_f32 %0, %1, %2, %3" : "=v"(bv) : "v"(bv), "v"(dn.x), "v"(dn.y));
            }

            // first-occurrence j among my 16 slots: descending overwrite -> min j
            int bj = 0;
#pragma unroll
            for (int j = PPT - 1; j >= 0; --j) {
                float dj = (j & 1) ? dist2[c][j >> 1].y : dist2[c][j >> 1].x;
                bj = (dj == bv) ? j : bj;
            }

            // wave64 value max via u32 DPP (bv >= 0 -> float bits monotone)
            unsigned khi = __float_as_uint(bv);
            unsigned r = khi;
            r = dpp_maxu<0xB1>(r);     // quad_perm xor1
            r = dpp_maxu<0x4E>(r);     // quad_perm xor2
            r = dpp_maxu<0x141>(r);    // row_half_mirror
            r = dpp_maxu<0x140>(r);    // row_mirror
            r = dpp_maxu<0x142>(r);    // row_bcast15
            r = dpp_maxu<0x143>(r);    // row_bcast31  -> lane63 holds wave max

            unsigned smax = (unsigned)__builtin_amdgcn_readlane((int)r, 63);
            unsigned long long mask = __ballot(khi == smax);   // nonzero by construction
            int sl = __builtin_ctzll(mask);                    // first lane == lowest idx
            int widx_w = __builtin_amdgcn_readlane(base + bj, sl);  // wave winner idx

            if (lane == 0)
                swk[c][buf][wave] = ((unsigned long long)smax << 32) |
                                    (unsigned)(N_PER - 1 - widx_w);   // tie -> min idx
        }

        __syncthreads();   // ONE barrier serves both clouds' steps

        // --- post-barrier: merge + dependent broadcast spos read, both clouds
        // (independent chains; key reads and spos reads pipeline across c)
#pragma unroll
        for (int c = 0; c < CPB; ++c) {
            unsigned long long k = swk[c][buf][0];
#pragma unroll
            for (int w = 1; w < NWAVE; ++w) {
                unsigned long long k2 = swk[c][buf][w];
                if (k2 > k) k = k2;
            }
            int widx = N_PER - 1 - (int)(unsigned)(k & 0xFFFu);
            float4 wp = spos[c][widx];     // broadcast ds_read_b128
            lx[c] = wp.x; ly[c] = wp.y; lz[c] = wp.z;
            if (tid == 0) sloc[c][s] = widx;   // LDS, drained at next barrier
        }
    }

    // dump sampled indices to global once (coalesced)
    __syncthreads();
#pragma unroll
    for (int c = 0; c < CPB; ++c)
        for (int i = tid; i < M_SAMP; i += TPB)
            sidx[(blockIdx.x * CPB + c) * M_SAMP + i] = sloc[c][i];
}

// ---------------------------------------------------------------------------
// Gather x rows: out[r][:] = x[g][:], float4-vectorized. 16384 rows x 128 f4.
// sidx holds LOCAL per-cloud indices; globalize with cloud offset r/M*N_PER.
// ---------------------------------------------------------------------------
__global__ __launch_bounds__(256) void gather_x_kernel(const float4* __restrict__ x4,
                                                       const int* __restrict__ sidx,
                                                       float4* __restrict__ out4) {
    int id = blockIdx.x * 256 + threadIdx.x;     // 0 .. 16384*128-1
    int r  = id >> 7;                            // row in output
    int c  = id & 127;                           // float4 column
    int g  = sidx[r] + (r >> 10 << 12);          // + (r/1024)*4096 global offset
    out4[id] = x4[(size_t)g * (D_FEAT / 4) + c];
}

// ---------------------------------------------------------------------------
// Gather pos (3 f32/row) and batch (as float). 16384 threads.
// ---------------------------------------------------------------------------
__global__ __launch_bounds__(256) void gather_pb_kernel(const float* __restrict__ pos,
                                                        const int* __restrict__ batch,
                                                        const int* __restrict__ sidx,
                                                        float* __restrict__ out_pos,
                                                        float* __restrict__ out_batch) {
    int r = blockIdx.x * 256 + threadIdx.x;      // 0 .. 16383
    int g = sidx[r] + (r >> 10 << 12);
    out_pos[r * 3 + 0] = pos[g * 3 + 0];
    out_pos[r * 3 + 1] = pos[g * 3 + 1];
    out_pos[r * 3 + 2] = pos[g * 3 + 2];
    out_batch[r] = (float)batch[g];
}

extern "C" void kernel_launch(void* const* d_in, const int* in_sizes, int n_in,
                              void* d_out, int out_size, void* d_ws, size_t ws_size,
                              hipStream_t stream) {
    const float* x     = (const float*)d_in[0];   // [65536,512] f32
    const float* pos   = (const float*)d_in[1];   // [65536,3]   f32
    const int*   batch = (const int*)d_in[2];     // [65536]     i32

    int* sidx = (int*)d_ws;                       // [16384] local sampled indices

    float* out   = (float*)d_out;
    float* out_x = out;                                            // 16384*512
    float* out_p = out + (size_t)B_CL * M_SAMP * D_FEAT;           // 16384*3
    float* out_b = out_p + (size_t)B_CL * M_SAMP * 3;              // 16384

    // 1) FPS: 8 blocks (two clouds per block), 256 threads
    fps_kernel<<<B_CL / CPB, TPB, 0, stream>>>(pos, sidx);

    // 2) x gather: 16384 rows * 128 float4 / 256 threads = 8192 blocks
    gather_x_kernel<<<(B_CL * M_SAMP * (D_FEAT / 4)) / 256, 256, 0, stream>>>(
        (const float4*)x, sidx, (float4*)out_x);

    // 3) pos + batch gather: 16384 / 256 = 64 blocks
    gather_pb_kernel<<<(B_CL * M_SAMP) / 256, 256, 0, stream>>>(
        pos, batch, sidx, out_p, out_b);
}

// Round 7
// 728.927 us; speedup vs baseline: 1.5905x; 1.5905x over previous
//
#include <hip/hip_runtime.h>

// Problem constants (from reference): 16 clouds x 4096 pts, sample 1024, D=512
#define N_PER   4096
#define M_SAMP  1024
#define B_CL    16
#define D_FEAT  512
#define TPB     256
#define NWAVE   (TPB / 64)      // 4 waves
#define PPT     (N_PER / TPB)   // 16 points per thread
#define NPAIR   (PPT / 2)       // 8 packed pairs per thread

typedef float v2f __attribute__((ext_vector_type(2)));

// ---------------------------------------------------------------------------
// u32 DPP max combine (value-only wave reduce). Lanes not supplied by the
// pattern combine with themselves (old == own value -> no-op).
// ---------------------------------------------------------------------------
template <int CTRL>
__device__ __forceinline__ unsigned dpp_maxu(unsigned v) {
    unsigned o = (unsigned)__builtin_amdgcn_update_dpp((int)v, (int)v, CTRL, 0xF, 0xF, false);
    return (o > v) ? o : v;
}

// ---------------------------------------------------------------------------
// FPS: one workgroup per cloud, 256 threads, 1 wave/SIMD. This is the
// verified-best R2 structure. Measured-dead alternatives (do NOT revisit):
//   R1 LDS-spin sync            +29%  (volatile poll serialization)
//   R3 2 waves/SIMD             +7%   (+270cy duplicated tail issue > -178cy
//                                      stall hiding)
//   R4 divergent coord ship     +14%  (bank conflicts 57K->898K)
//   R5 pre-barrier coord ship   +10%  (lgkm drain on barrier-approach path)
//   R6 2 clouds/block           +80%  (halved CUs, tail < inner issue)
// This round adds only: 2x b128 key reads (was 4x b64) + pairwise-tree merge.
//
// Exactness:
//  - distance math contract(off), same op order -> bit-exact d2 chain
//  - value-only in-loop max via v_max3_f32; first-occurrence index by
//    descending equality scan (min j wins)
//  - wave reduce: 6-stage u32 DPP max on float bits (all dist >= 0)
//  - winner lane via readlane(63) -> ballot -> ctz (lane order == idx order)
//  - cross-wave merge via u64 keys (dist bits << 32 | (4095 - idx)):
//    max key == max dist, tie -> smaller global idx (jnp.argmax semantics);
//    keys unique -> max is exact under any association.
// ---------------------------------------------------------------------------
__global__ __launch_bounds__(TPB)
__attribute__((amdgpu_waves_per_eu(1, 1)))
void fps_kernel(const float* __restrict__ pos, int* __restrict__ sidx) {
    __shared__ float4 spos[N_PER];                            // 64 KiB coord table
    __shared__ alignas(16) unsigned long long swk[2][NWAVE];  // dbuf wave keys
    __shared__ int sloc[M_SAMP];                              // sampled local idx

    const int cloud = blockIdx.x;
    const int tid   = threadIdx.x;
    const float* posb = pos + (size_t)cloud * N_PER * 3;

    // preload my 16 points (12 aligned float4 from global), pack into v2f regs,
    // and stage the same points into spos (one-time)
    v2f px2[NPAIR], py2[NPAIR], pz2[NPAIR], dist2[NPAIR];
    const int base = tid * PPT;
    {
        float f[48];
        const float4* posb4 = (const float4*)posb + tid * 12;
#pragma unroll
        for (int v = 0; v < 12; ++v) {
            float4 t = posb4[v];
            f[4 * v + 0] = t.x; f[4 * v + 1] = t.y;
            f[4 * v + 2] = t.z; f[4 * v + 3] = t.w;
        }
#pragma unroll
        for (int p = 0; p < NPAIR; ++p) {
            px2[p] = (v2f){f[6 * p + 0], f[6 * p + 3]};
            py2[p] = (v2f){f[6 * p + 1], f[6 * p + 4]};
            pz2[p] = (v2f){f[6 * p + 2], f[6 * p + 5]};
            dist2[p] = (v2f){1e30f, 1e30f};
        }
#pragma unroll
        for (int j = 0; j < PPT; ++j)
            spos[base + j] = make_float4(f[3 * j], f[3 * j + 1], f[3 * j + 2], 0.0f);
    }

    float lx = posb[0], ly = posb[1], lz = posb[2];   // start point = local 0
    if (tid == 0) sloc[0] = 0;

    const int wave = tid >> 6;
    const int lane = tid & 63;
    __syncthreads();   // spos visible

    for (int s = 1; s < M_SAMP; ++s) {
        float bv = -1.0f;     // all dist >= 0, so always beaten
        v2f lxv = {lx, lx}, lyv = {ly, ly}, lzv = {lz, lz};
#pragma unroll
        for (int p = 0; p < NPAIR; ++p) {
#pragma clang fp contract(off)
            v2f dx = px2[p] - lxv;
            v2f dy = py2[p] - lyv;
            v2f dz = pz2[p] - lzv;
            v2f d2 = dx * dx + dy * dy + dz * dz;          // contract off: exact jnp order
            v2f dn = __builtin_elementwise_min(dist2[p], d2);
            dist2[p] = dn;
            // value-only running max: one v_max3_f32 per pair
            asm("v_max3_f32 %0, %1, %2, %3" : "=v"(bv) : "v"(bv), "v"(dn.x), "v"(dn.y));
        }

        // first-occurrence j among my 16 slots: descending overwrite -> min j
        // (independent of the DPP chain below; scheduler fills its bubbles)
        int bj = 0;
#pragma unroll
        for (int j = PPT - 1; j >= 0; --j) {
            float dj = (j & 1) ? dist2[j >> 1].y : dist2[j >> 1].x;
            bj = (dj == bv) ? j : bj;
        }

        // wave64 value max via u32 DPP (bv >= 0 -> float bits monotone)
        unsigned khi = __float_as_uint(bv);
        unsigned r = khi;
        r = dpp_maxu<0xB1>(r);     // quad_perm xor1
        r = dpp_maxu<0x4E>(r);     // quad_perm xor2
        r = dpp_maxu<0x141>(r);    // row_half_mirror
        r = dpp_maxu<0x140>(r);    // row_mirror
        r = dpp_maxu<0x142>(r);    // row_bcast15
        r = dpp_maxu<0x143>(r);    // row_bcast31  -> lane63 holds wave max

        unsigned smax = (unsigned)__builtin_amdgcn_readlane((int)r, 63);
        unsigned long long mask = __ballot(khi == smax);   // nonzero by construction
        int sl = __builtin_ctzll(mask);                    // first lane == lowest idx
        int widx_w = __builtin_amdgcn_readlane(base + bj, sl);  // wave winner idx

        const int buf = s & 1;
        if (lane == 0)
            swk[buf][wave] = ((unsigned long long)smax << 32) |
                             (unsigned)(N_PER - 1 - widx_w);   // tie -> min idx wins
        __syncthreads();   // only LDS outstanding -> cheap lgkm drain

        // cross-wave merge: 2x b128 broadcast reads + pairwise tree (depth 2)
        const ulonglong2* kp = (const ulonglong2*)&swk[buf][0];
        ulonglong2 kA = kp[0], kB = kp[1];
        unsigned long long m01 = (kA.y > kA.x) ? kA.y : kA.x;
        unsigned long long m23 = (kB.y > kB.x) ? kB.y : kB.x;
        unsigned long long k   = (m23 > m01) ? m23 : m01;

        int widx = N_PER - 1 - (int)(unsigned)(k & 0xFFFu);
        float4 wp = spos[widx];            // broadcast ds_read_b128
        lx = wp.x; ly = wp.y; lz = wp.z;
        if (tid == 0) sloc[s] = widx;      // LDS, drained at next barrier
    }

    // dump sampled indices to global once (coalesced)
    __syncthreads();
    for (int i = tid; i < M_SAMP; i += TPB)
        sidx[cloud * M_SAMP + i] = sloc[i];
}

// ---------------------------------------------------------------------------
// Gather x rows: out[r][:] = x[g][:], float4-vectorized. 16384 rows x 128 f4.
// sidx holds LOCAL per-cloud indices; globalize with cloud offset r/M*N_PER.
// ---------------------------------------------------------------------------
__global__ __launch_bounds__(256) void gather_x_kernel(const float4* __restrict__ x4,
                                                       const int* __restrict__ sidx,
                                                       float4* __restrict__ out4) {
    int id = blockIdx.x * 256 + threadIdx.x;     // 0 .. 16384*128-1
    int r  = id >> 7;                            // row in output
    int c  = id & 127;                           // float4 column
    int g  = sidx[r] + (r >> 10 << 12);          // + (r/1024)*4096 global offset
    out4[id] = x4[(size_t)g * (D_FEAT / 4) + c];
}

// ---------------------------------------------------------------------------
// Gather pos (3 f32/row) and batch (as float). 16384 threads.
// ---------------------------------------------------------------------------
__global__ __launch_bounds__(256) void gather_pb_kernel(const float* __restrict__ pos,
                                                        const int* __restrict__ batch,
                                                        const int* __restrict__ sidx,
                                                        float* __restrict__ out_pos,
                                                        float* __restrict__ out_batch) {
    int r = blockIdx.x * 256 + threadIdx.x;      // 0 .. 16383
    int g = sidx[r] + (r >> 10 << 12);
    out_pos[r * 3 + 0] = pos[g * 3 + 0];
    out_pos[r * 3 + 1] = pos[g * 3 + 1];
    out_pos[r * 3 + 2] = pos[g * 3 + 2];
    out_batch[r] = (float)batch[g];
}

extern "C" void kernel_launch(void* const* d_in, const int* in_sizes, int n_in,
                              void* d_out, int out_size, void* d_ws, size_t ws_size,
                              hipStream_t stream) {
    const float* x     = (const float*)d_in[0];   // [65536,512] f32
    const float* pos   = (const float*)d_in[1];   // [65536,3]   f32
    const int*   batch = (const int*)d_in[2];     // [65536]     i32

    int* sidx = (int*)d_ws;                       // [16384] local sampled indices

    float* out   = (float*)d_out;
    float* out_x = out;                                            // 16384*512
    float* out_p = out + (size_t)B_CL * M_SAMP * D_FEAT;           // 16384*3
    float* out_b = out_p + (size_t)B_CL * M_SAMP * 3;              // 16384

    // 1) FPS: 16 blocks (one per cloud), 256 threads
    fps_kernel<<<B_CL, TPB, 0, stream>>>(pos, sidx);

    // 2) x gather: 16384 rows * 128 float4 / 256 threads = 8192 blocks
    gather_x_kernel<<<(B_CL * M_SAMP * (D_FEAT / 4)) / 256, 256, 0, stream>>>(
        (const float4*)x, sidx, (float4*)out_x);

    // 3) pos + batch gather: 16384 / 256 = 64 blocks
    gather_pb_kernel<<<(B_CL * M_SAMP) / 256, 256, 0, stream>>>(
        pos, batch, sidx, out_p, out_b);
}